// Round 3
// baseline (89.546 us; speedup 1.0000x reference)
//
#include <hip/hip_runtime.h>
#include <hip/hip_bf16.h>

// LocallyConnected2d: out[i][j] = sum_{p=0..255} x[i + p/16][j + p%16] * W[i][j][p]
// x: (512,512) f32 (1 MB, cache-resident), W: (497,497,256) f32 (253 MB, streamed once),
// out: (497,497) f32.
//
// HBM-bound on W. Structure: 4 positions per wave, 16 lanes per position.
// Lane l -> position sub=l>>4, kernel row q=l&15. Each lane loads 64 B of W
// (4x float4, nontemporal: W has zero reuse) and the matching 16-float x row
// segment, does 16 FMAs, then a 4-deep shfl_xor reduce within its 16-lane
// group. vs round 0: shuffle chain 6->4 deep per 4x the bytes (6x fewer
// shuffles/KiB), 4x more W bytes in flight per iteration.

constexpr int IN_H  = 512;
constexpr int IN_W  = 512;
constexpr int KH    = 16;
constexpr int KW    = 16;
constexpr int KK    = KH * KW;          // 256
constexpr int OUT_H = IN_H - KH + 1;    // 497
constexpr int OUT_W = IN_W - KW + 1;    // 497
constexpr int NPOS  = OUT_H * OUT_W;    // 247009
constexpr int NCHUNK = (NPOS + 3) / 4;  // 61753 (last chunk is partial)

// Native vector type: __builtin_nontemporal_load requires scalar/native-vector
// pointee (HIP_vector_type float4 is a struct -> rejected).
typedef float f32x4 __attribute__((ext_vector_type(4)));

static __device__ __forceinline__ f32x4 ldx4(const float* p) {
    // x addresses are only 4 B aligned (j arbitrary) — alignment-safe load.
    f32x4 v;
    __builtin_memcpy(&v, p, sizeof(f32x4));
    return v;
}

__global__ __launch_bounds__(256, 8)
void lc2d_kernel(const float* __restrict__ x,
                 const float* __restrict__ W,
                 float* __restrict__ out) {
    const int lane = threadIdx.x & 63;
    const int wid  = (blockIdx.x * blockDim.x + threadIdx.x) >> 6;
    const int nw   = (gridDim.x * blockDim.x) >> 6;

    const int sub = lane >> 4;   // which of the 4 positions in this chunk
    const int q   = lane & 15;   // kernel row (kh) handled by this lane

    for (int c = wid; c < NCHUNK; c += nw) {
        int pos = (c << 2) + sub;
        const bool valid = pos < NPOS;
        if (!valid) pos = NPOS - 1;          // clamp: redundant load, no store

        const int i = pos / OUT_W;           // magic-mul
        const int j = pos - i * OUT_W;

        // W: lane reads 64 B at byte offset pos*1024 + q*64 (16 B aligned).
        // Wave covers 4 KiB contiguous. Nontemporal: W is used exactly once.
        const f32x4* wp = reinterpret_cast<const f32x4*>(W + (size_t)pos * KK + (q << 4));
        const f32x4 w0 = __builtin_nontemporal_load(wp + 0);
        const f32x4 w1 = __builtin_nontemporal_load(wp + 1);
        const f32x4 w2 = __builtin_nontemporal_load(wp + 2);
        const f32x4 w3 = __builtin_nontemporal_load(wp + 3);

        // x: row i+q, columns j..j+15 (L1/L2-hit; rows reused across the 4 subs).
        const float* xp = x + (i + q) * IN_W + j;
        const f32x4 x0 = ldx4(xp + 0);
        const f32x4 x1 = ldx4(xp + 4);
        const f32x4 x2 = ldx4(xp + 8);
        const f32x4 x3 = ldx4(xp + 12);

        float s = w0.x * x0.x + w0.y * x0.y + w0.z * x0.z + w0.w * x0.w
                + w1.x * x1.x + w1.y * x1.y + w1.z * x1.z + w1.w * x1.w
                + w2.x * x2.x + w2.y * x2.y + w2.z * x2.z + w2.w * x2.w
                + w3.x * x3.x + w3.y * x3.y + w3.z * x3.z + w3.w * x3.w;

        // Reduce across the 16 kernel rows (within each 16-lane group).
        s += __shfl_xor(s, 1, 64);
        s += __shfl_xor(s, 2, 64);
        s += __shfl_xor(s, 4, 64);
        s += __shfl_xor(s, 8, 64);

        if (q == 0 && valid) out[pos] = s;   // lanes 0,16,32,48 -> 4 consecutive floats
    }
}

extern "C" void kernel_launch(void* const* d_in, const int* in_sizes, int n_in,
                              void* d_out, int out_size, void* d_ws, size_t ws_size,
                              hipStream_t stream) {
    const float* x = (const float*)d_in[0];
    const float* W = (const float*)d_in[1];
    float* out     = (float*)d_out;

    // 2048 blocks x 256 threads = 8192 waves (8/SIMD), ~7.5 chunks per wave.
    const int threads = 256;
    const int blocks  = 2048;
    lc2d_kernel<<<blocks, threads, 0, stream>>>(x, W, out);
}

// Round 4
// 46.205 us; speedup vs baseline: 1.9380x; 1.9380x over previous
//
#include <hip/hip_runtime.h>
#include <hip/hip_bf16.h>

// LocallyConnected2d: out[i][j] = sum_{p=0..255} x[i + p/16][j + p%16] * W[i][j][p]
// x: (512,512) f32 (1 MB, cache-hot), W: (497,497,256) f32 (253 MB, streamed once).
//
// Limiter analysis (R0/R2): TA line-request throughput, not HBM. Scalar x
// gathers spanning 16 rows cost ~96 line-cycles per KiB of W (R0 = 5.3 TB/s);
// per-lane-contiguous W loads cost 4x line-requests (R2 = 2x slower).
// This round: W keeps the perfect mapping (one instruction = one position's
// contiguous 1 KiB, lane l -> taps 4l..4l+3, 16 lines/instr) and x moves to
// LDS: stage rows i..i+15, cols j0..j0+79 once per block (64-position row
// segment), lanes read their 4 taps from the LDS pipe instead of VMEM.
// LDS row stride 83 => bank pattern (19*row + 4*k) mod 32 is max 2-way (free).

constexpr int IN_W  = 512;
constexpr int KH    = 16;
constexpr int KK    = 256;          // 16*16 taps
constexpr int OUT_W = 497;
constexpr int SEG       = 64;       // output positions per block (one row segment)
constexpr int TILE_COLS = 80;       // x cols staged: j0 .. j0+79 (need 79)
constexpr int TILE_S    = 83;       // LDS row stride (83 mod 32 = 19, coprime-ish)

typedef float f32x4 __attribute__((ext_vector_type(4)));

__global__ __launch_bounds__(256, 4)
void lc2d_kernel(const float* __restrict__ x,
                 const float* __restrict__ W,
                 float* __restrict__ out) {
    __shared__ float xt[KH * TILE_S];

    const int i   = blockIdx.x >> 3;         // output row       (497 rows)
    const int j0  = (blockIdx.x & 7) << 6;   // segment start col (8 segs/row)
    const int tid = threadIdx.x;

    // Stage x strip: rows i..i+15, cols j0..j0+79 (col-clamped; rows always
    // in bounds since i <= 496 -> i+15 <= 511). ~1280 L2-hit floats, coalesced.
    for (int idx = tid; idx < KH * TILE_COLS; idx += 256) {
        const int r  = idx / TILE_COLS;          // const-div -> magic mul
        const int c  = idx - r * TILE_COLS;
        int gc = j0 + c; if (gc > IN_W - 1) gc = IN_W - 1;
        xt[r * TILE_S + c] = x[(i + r) * IN_W + gc];
    }
    __syncthreads();

    const int lane = tid & 63;
    const int w    = tid >> 6;               // wave 0..3 -> cols j0+16w..+15
    const int row  = lane >> 2;              // kernel row owned by this lane
    const int kw   = (lane & 3) << 2;        // kernel col base (0,4,8,12)
    const float* xrow = &xt[row * TILE_S + (w << 4) + kw];

    #pragma unroll
    for (int t = 0; t < 16; ++t) {
        const int jj = j0 + (w << 4) + t;    // wave-uniform bound check
        if (jj < OUT_W) {
            const int pos = i * OUT_W + jj;
            // One instruction = one position's contiguous 1 KiB of W.
            const f32x4 wv = __builtin_nontemporal_load(
                reinterpret_cast<const f32x4*>(W + (size_t)pos * KK) + lane);
            const float* xp = xrow + t;      // LDS: 4 x taps, max 2-way banks
            float s = wv.x * xp[0] + wv.y * xp[1] + wv.z * xp[2] + wv.w * xp[3];
            // 64-lane butterfly; chains across unrolled t are independent.
            s += __shfl_xor(s, 1, 64);
            s += __shfl_xor(s, 2, 64);
            s += __shfl_xor(s, 4, 64);
            s += __shfl_xor(s, 8, 64);
            s += __shfl_xor(s, 16, 64);
            s += __shfl_xor(s, 32, 64);
            if (lane == 0) out[pos] = s;
        }
    }
}

extern "C" void kernel_launch(void* const* d_in, const int* in_sizes, int n_in,
                              void* d_out, int out_size, void* d_ws, size_t ws_size,
                              hipStream_t stream) {
    const float* x = (const float*)d_in[0];
    const float* W = (const float*)d_in[1];
    float* out     = (float*)d_out;

    // One block per 64-wide row segment: 497 rows x 8 segments = 3976 blocks.
    const int blocks = 497 * 8;
    lc2d_kernel<<<blocks, 256, 0, stream>>>(x, W, out);
}

// Round 5
// 45.096 us; speedup vs baseline: 1.9857x; 1.0246x over previous
//
#include <hip/hip_runtime.h>
#include <hip/hip_bf16.h>

// LocallyConnected2d: out[i][j] = sum_{p=0..255} x[i + p/16][j + p%16] * W[i][j][p]
// x: (512,512) f32 (cache-hot), W: (497,497,256) f32 (253 MB streamed once).
//
// R0/R3 post-mortem: x-path and occupancy are NOT the limiter (both ~46-48us).
// Remaining per-position cost was the 6-deep shfl_xor chain + x LDS reads.
// This round: per position = 1 VMEM (wave reads the position's contiguous
// 1 KiB, lane l -> taps 4l..4l+3) + 4 FMA. Each lane holds a 19-float x
// register window (its kernel row, cols sliding with t) loaded once per 16
// positions; the 64-lane reduce is done ONCE per 16 positions via an LDS
// transpose (4x ds_write_b128 + 16x ds_read_b32 + 2 shuffles).

constexpr int IN_W  = 512;
constexpr int KH    = 16;
constexpr int KK    = 256;          // taps per position
constexpr int OUT_W = 497;
constexpr int TILE_COLS = 80;       // x cols staged per block
constexpr int TILE_S    = 84;       // x tile row stride (336 B, 16B-multiple)
constexpr int XPO_S     = 20;       // transpose row stride (80 B, 16B-multiple)

typedef float f32x4 __attribute__((ext_vector_type(4)));

__global__ __launch_bounds__(256)
void lc2d_kernel(const float* __restrict__ x,
                 const float* __restrict__ W,
                 float* __restrict__ out) {
    __shared__ float xt[KH * TILE_S];        // 5.4 KB
    __shared__ float xpose[4][64 * XPO_S];   // 20.5 KB (per-wave regions)

    const int i   = blockIdx.x >> 3;         // output row
    const int j0  = (blockIdx.x & 7) << 6;   // 64-col segment base
    const int tid = threadIdx.x;

    // Stage x rows i..i+15, cols j0..j0+79 (col-clamped; rows always valid).
    for (int idx = tid; idx < KH * TILE_COLS; idx += 256) {
        const int r = idx / TILE_COLS;
        const int c = idx - r * TILE_COLS;
        int gc = j0 + c; if (gc > IN_W - 1) gc = IN_W - 1;
        xt[r * TILE_S + c] = x[(i + r) * IN_W + gc];
    }
    __syncthreads();

    const int lane = tid & 63;
    const int w    = tid >> 6;            // wave -> cols jw..jw+15
    const int kh   = lane >> 2;           // this lane's kernel row
    const int kw   = (lane & 3) << 2;     // this lane's kernel col base
    const int jw   = j0 + (w << 4);

    // Per-lane x register window: xt[kh][16w+kw .. +19] (5 aligned b128 reads).
    float xw[20];
    {
        const float* base = &xt[kh * TILE_S + (w << 4) + kw];
        #pragma unroll
        for (int g = 0; g < 5; ++g) {
            const f32x4 v = *reinterpret_cast<const f32x4*>(base + 4 * g);
            xw[4*g+0] = v.x; xw[4*g+1] = v.y; xw[4*g+2] = v.z; xw[4*g+3] = v.w;
        }
    }

    // 16 positions: 1 VMEM + 4 FMA each. Static window indices (full unroll).
    float s[16];
    #pragma unroll
    for (int t = 0; t < 16; ++t) {
        int jj = jw + t; if (jj > OUT_W - 1) jj = OUT_W - 1;   // uniform clamp
        const size_t pos = (size_t)i * OUT_W + jj;
        const f32x4 wv = __builtin_nontemporal_load(
            reinterpret_cast<const f32x4*>(W + pos * KK) + lane);
        s[t] = wv.x * xw[t] + wv.y * xw[t+1] + wv.z * xw[t+2] + wv.w * xw[t+3];
    }

    // Transpose-reduce (once per 16 positions): lane writes its 16 partials
    // as a row; then 4 lanes per position sum 16 entries each; 2 shuffles.
    float* xp = &xpose[w][0];
    #pragma unroll
    for (int g = 0; g < 4; ++g) {
        const f32x4 v = { s[4*g+0], s[4*g+1], s[4*g+2], s[4*g+3] };
        *reinterpret_cast<f32x4*>(xp + lane * XPO_S + 4 * g) = v;  // 2-way banks
    }
    __syncthreads();   // uniform; orders LDS for the cross-lane read

    const int t = lane & 15;     // position this lane finishes
    const int q = lane >> 4;     // quarter of the 64 partial lanes
    float r = 0.f;
    #pragma unroll
    for (int e = 0; e < 16; ++e)
        r += xp[(q * 16 + e) * XPO_S + t];
    r += __shfl_xor(r, 16, 64);
    r += __shfl_xor(r, 32, 64);

    const int jj = jw + t;
    if (q == 0 && jj < OUT_W)
        out[(size_t)i * OUT_W + jj] = r;   // 16 consecutive floats per wave
}

extern "C" void kernel_launch(void* const* d_in, const int* in_sizes, int n_in,
                              void* d_out, int out_size, void* d_ws, size_t ws_size,
                              hipStream_t stream) {
    const float* x = (const float*)d_in[0];
    const float* W = (const float*)d_in[1];
    float* out     = (float*)d_out;

    // One block per 64-wide row segment: 497 rows x 8 segments.
    lc2d_kernel<<<497 * 8, 256, 0, stream>>>(x, W, out);
}